// Round 1
// baseline (118.105 us; speedup 1.0000x reference)
//
#include <hip/hip_runtime.h>
#include <hip/hip_bf16.h>
#include <math.h>

#define NRES   4096
#define NBATCH 1024
#define NIN    128
#define NOUT   64
// K layout: [0,4096) x/W_res bf16 | [4096,4224) hiP*hiW | [4224,4352) hiP*loW
//           [4352,4480) loP*hiW | [4480,4544) hiT*hiWo | [4544,4608) hiT*loWo | [4608,4672) loT*hiWo
#define KT     4672
#define BM 128
#define BN 128
#define BK 64

typedef __bf16 bf16x8 __attribute__((ext_vector_type(8)));
typedef float  f32x4  __attribute__((ext_vector_type(4)));

__device__ __forceinline__ float lo_part(float f) {
    return f - (float)(__bf16)f;
}

__device__ __forceinline__ void gload_lds16(const void* g, void* l) {
    __builtin_amdgcn_global_load_lds(
        (const __attribute__((address_space(1))) unsigned int*)g,
        (__attribute__((address_space(3))) unsigned int*)l, 16, 0, 0);
}

__global__ __launch_bounds__(256) void pack_A_kernel(
    const float* __restrict__ x, const float* __restrict__ passed,
    const float* __restrict__ lastOut, const float* __restrict__ lastPred,
    const float* __restrict__ prob, const float* __restrict__ rand_num,
    __bf16* __restrict__ Abuf)
{
    unsigned id = blockIdx.x * 256u + threadIdx.x;
    if (id >= (unsigned)NBATCH * KT) return;
    unsigned b = id / KT;
    unsigned k = id - b * KT;
    float v;
    if (k < 4096u) {
        v = x[(size_t)b * NRES + k];
    } else if (k < 4224u) {
        v = passed[b * NIN + (k - 4096u)];            // hi
    } else if (k < 4352u) {
        v = passed[b * NIN + (k - 4224u)];            // hi (pairs loW)
    } else if (k < 4480u) {
        v = lo_part(passed[b * NIN + (k - 4352u)]);   // lo
    } else {
        bool sel = rand_num[0] < prob[0];
        unsigned j; bool want_lo;
        if (k < 4544u)      { j = k - 4480u; want_lo = false; }
        else if (k < 4608u) { j = k - 4544u; want_lo = false; }
        else                { j = k - 4608u; want_lo = true;  }
        float f = sel ? lastOut[j * NBATCH + b] : lastPred[j * NBATCH + b];
        v = want_lo ? lo_part(f) : f;
    }
    Abuf[id] = (__bf16)v;
}

__global__ __launch_bounds__(256) void pack_B_kernel(
    const float* __restrict__ W_res, const float* __restrict__ W_in,
    const float* __restrict__ W_out, __bf16* __restrict__ Bbuf)
{
    unsigned id = blockIdx.x * 256u + threadIdx.x;
    if (id >= (unsigned)NRES * KT) return;
    unsigned n = id / KT;
    unsigned k = id - n * KT;
    float v;
    if (k < 4096u)      v = W_res[(size_t)n * NRES + k];
    else if (k < 4224u) v = W_in[n * NIN + (k - 4096u)];           // hi
    else if (k < 4352u) v = lo_part(W_in[n * NIN + (k - 4224u)]);  // lo (pairs hiP)
    else if (k < 4480u) v = W_in[n * NIN + (k - 4352u)];           // hi (pairs loP)
    else if (k < 4544u) v = W_out[n * NOUT + (k - 4480u)];         // hi
    else if (k < 4608u) v = lo_part(W_out[n * NOUT + (k - 4544u)]);// lo
    else                v = W_out[n * NOUT + (k - 4608u)];         // hi
    Bbuf[id] = (__bf16)v;
}

__global__ __launch_bounds__(512, 1) void gemm_kernel(
    const __bf16* __restrict__ Abuf, const __bf16* __restrict__ Bbuf,
    const float* __restrict__ xin, const float* __restrict__ Bin,
    float* __restrict__ out)
{
    __shared__ __align__(16) __bf16 As[BM * BK];
    __shared__ __align__(16) __bf16 Bs[BN * BK];

    const int t  = threadIdx.x;
    const int l  = t & 63;
    const int w  = t >> 6;
    const int wr = w >> 2;   // 0..1  (64-row slab)
    const int wc = w & 3;    // 0..3  (32-col slab)
    const int bm = blockIdx.y;
    const int bn = blockIdx.x;

    f32x4 acc[4][2] = {};

    // Staging: 1024 16B-chunks per tile, 512 threads -> 2 chunks each for A and B.
    // LDS dest is LINEAR (global_load_lds requirement); the XOR swizzle is applied
    // to the global SOURCE column so that swizzled ds_reads see correct data.
    const __bf16* srcA[2];
    const __bf16* srcB[2];
    void* dstA[2];
    void* dstB[2];
#pragma unroll
    for (int j = 0; j < 2; ++j) {
        int ca  = j * 512 + t;             // chunk id 0..1023
        int row = ca >> 3;                 // 0..127
        int cb  = (ca & 7) << 4;           // byte-in-row 0..112
        int cs  = cb ^ ((row & 7) << 4);   // swizzled source byte
        srcA[j] = Abuf + (size_t)(bm * BM + row) * KT + (cs >> 1);
        srcB[j] = Bbuf + (size_t)(bn * BN + row) * KT + (cs >> 1);
        dstA[j] = (char*)As + ca * 16;
        dstB[j] = (char*)Bs + ca * 16;
    }

    // Fragment read byte-offsets (swizzled to match the staged layout)
    int offA[4][2], offB[2][2];
#pragma unroll
    for (int m = 0; m < 4; ++m) {
        int row = wr * 64 + m * 16 + (l & 15);
#pragma unroll
        for (int kk = 0; kk < 2; ++kk) {
            int cb = (kk * 64 + ((l >> 4) << 4)) ^ ((row & 7) << 4);
            offA[m][kk] = row * 128 + cb;
        }
    }
#pragma unroll
    for (int n = 0; n < 2; ++n) {
        int row = wc * 32 + n * 16 + (l & 15);
#pragma unroll
        for (int kk = 0; kk < 2; ++kk) {
            int cb = (kk * 64 + ((l >> 4) << 4)) ^ ((row & 7) << 4);
            offB[n][kk] = row * 128 + cb;
        }
    }

    for (int k0 = 0; k0 < KT; k0 += BK) {
#pragma unroll
        for (int j = 0; j < 2; ++j) {
            gload_lds16(srcA[j] + k0, dstA[j]);
            gload_lds16(srcB[j] + k0, dstB[j]);
        }
        __syncthreads();   // compiler drains vmcnt(0) before s_barrier
#pragma unroll
        for (int kk = 0; kk < 2; ++kk) {
            bf16x8 af[4], bv[2];
#pragma unroll
            for (int m = 0; m < 4; ++m)
                af[m] = *(const bf16x8*)((const char*)As + offA[m][kk]);
#pragma unroll
            for (int n = 0; n < 2; ++n)
                bv[n] = *(const bf16x8*)((const char*)Bs + offB[n][kk]);
#pragma unroll
            for (int m = 0; m < 4; ++m)
#pragma unroll
                for (int n = 0; n < 2; ++n)
                    acc[m][n] = __builtin_amdgcn_mfma_f32_16x16x32_bf16(
                        af[m], bv[n], acc[m][n], 0, 0, 0);
        }
        __syncthreads();   // protect LDS before next stage
    }

    // Epilogue: out = 0.1*x + 0.9*tanh(acc + B_in)
    // C/D layout: col = lane&15, row = (lane>>4)*4 + reg  [m89/m91-verified]
    const int col0 = bn * BN + wc * 32 + (l & 15);
    const int row0 = bm * BM + wr * 64 + ((l >> 4) << 2);
#pragma unroll
    for (int m = 0; m < 4; ++m) {
#pragma unroll
        for (int i = 0; i < 4; ++i) {
            int r = row0 + m * 16 + i;
            const float* xr  = xin + (size_t)r * NRES;
            float*       orow = out + (size_t)r * NRES;
#pragma unroll
            for (int n = 0; n < 2; ++n) {
                int c = col0 + n * 16;
                float pre = acc[m][n][i] + Bin[c];
                orow[c] = 0.1f * xr[c] + 0.9f * tanhf(pre);
            }
        }
    }
}

extern "C" void kernel_launch(void* const* d_in, const int* in_sizes, int n_in,
                              void* d_out, int out_size, void* d_ws, size_t ws_size,
                              hipStream_t stream) {
    (void)in_sizes; (void)n_in; (void)out_size; (void)ws_size;
    const float* passed     = (const float*)d_in[0];
    const float* lastOutput = (const float*)d_in[1];
    const float* lastPred   = (const float*)d_in[2];
    const float* x          = (const float*)d_in[3];
    const float* prob       = (const float*)d_in[4];
    const float* rand_num   = (const float*)d_in[5];
    const float* W_in       = (const float*)d_in[6];
    const float* W_res      = (const float*)d_in[7];
    const float* W_out      = (const float*)d_in[8];
    const float* B_in       = (const float*)d_in[9];
    float* out = (float*)d_out;

    __bf16* Abuf = (__bf16*)d_ws;                                   // 1024*4672*2 = 9,568,256 B
    __bf16* Bbuf = (__bf16*)((char*)d_ws + (size_t)NBATCH * KT * 2); // 4096*4672*2 = 38,273,024 B

    pack_A_kernel<<<(NBATCH * KT) / 256, 256, 0, stream>>>(
        x, passed, lastOutput, lastPred, prob, rand_num, Abuf);
    pack_B_kernel<<<(NRES * KT) / 256, 256, 0, stream>>>(
        W_res, W_in, W_out, Bbuf);

    dim3 grid(NRES / BN, NBATCH / BM);
    gemm_kernel<<<grid, 512, 0, stream>>>(Abuf, Bbuf, x, B_in, out);
}

// Round 2
// 100.279 us; speedup vs baseline: 1.1778x; 1.1778x over previous
//
#include <hip/hip_runtime.h>
#include <hip/hip_bf16.h>
#include <math.h>

#define NRES   4096
#define NBATCH 1024
#define NIN    128
#define NOUT   64
// K layout: [0,4096) x/W_res bf16 | [4096,4224) hiP*hiW | [4224,4352) hiP*loW
//           [4352,4480) loP*hiW | [4480,4544) hiT*hiWo | [4544,4608) hiT*loWo | [4608,4672) loT*hiWo
#define KT     4672
#define KQ     (KT / 4)
#define BM 128
#define BN 128
#define BK 64
#define NT (KT / BK)   // 73 K-steps

typedef __bf16 bf16x8 __attribute__((ext_vector_type(8)));
typedef __bf16 bf16x4 __attribute__((ext_vector_type(4)));
typedef float  f32x4  __attribute__((ext_vector_type(4)));

__device__ __forceinline__ float lo_part(float f) {
    return f - (float)(__bf16)f;
}

__device__ __forceinline__ void gload_lds16(const void* g, void* l) {
    __builtin_amdgcn_global_load_lds(
        (const __attribute__((address_space(1))) unsigned int*)g,
        (__attribute__((address_space(3))) unsigned int*)l, 16, 0, 0);
}

__global__ __launch_bounds__(256) void pack_A4(
    const float* __restrict__ x, const float* __restrict__ passed,
    const float* __restrict__ lastOut, const float* __restrict__ lastPred,
    const float* __restrict__ prob, const float* __restrict__ rand_num,
    __bf16* __restrict__ Abuf)
{
    unsigned id = blockIdx.x * 256u + threadIdx.x;
    if (id >= (unsigned)NBATCH * KQ) return;
    unsigned b = id / KQ;
    unsigned k = (id - b * KQ) * 4u;
    f32x4 v;
    if (k < 4096u) {
        v = *(const f32x4*)(x + (size_t)b * NRES + k);
    } else if (k < 4224u) {
        v = *(const f32x4*)(passed + b * NIN + (k - 4096u));            // hi
    } else if (k < 4352u) {
        v = *(const f32x4*)(passed + b * NIN + (k - 4224u));            // hi (pairs loW)
    } else if (k < 4480u) {
        f32x4 f = *(const f32x4*)(passed + b * NIN + (k - 4352u));      // lo
#pragma unroll
        for (int e = 0; e < 4; ++e) v[e] = lo_part(f[e]);
    } else {
        const float* src = (rand_num[0] < prob[0]) ? lastOut : lastPred;
#pragma unroll
        for (int e = 0; e < 4; ++e) {
            unsigned kk = k + e;
            unsigned j; bool want_lo;
            if (kk < 4544u)      { j = kk - 4480u; want_lo = false; }
            else if (kk < 4608u) { j = kk - 4544u; want_lo = false; }
            else                 { j = kk - 4608u; want_lo = true;  }
            float f = src[j * NBATCH + b];
            v[e] = want_lo ? lo_part(f) : f;
        }
    }
    bf16x4 o;
#pragma unroll
    for (int e = 0; e < 4; ++e) o[e] = (__bf16)v[e];
    *(bf16x4*)(Abuf + (size_t)id * 4u) = o;
}

__global__ __launch_bounds__(256) void pack_B4(
    const float* __restrict__ W_res, const float* __restrict__ W_in,
    const float* __restrict__ W_out, __bf16* __restrict__ Bbuf)
{
    unsigned id = blockIdx.x * 256u + threadIdx.x;
    if (id >= (unsigned)NRES * KQ) return;
    unsigned n = id / KQ;
    unsigned k = (id - n * KQ) * 4u;
    f32x4 v;
    if (k < 4096u) {
        v = *(const f32x4*)(W_res + (size_t)n * NRES + k);
    } else if (k < 4224u) {
        v = *(const f32x4*)(W_in + n * NIN + (k - 4096u));              // hi
    } else if (k < 4352u) {
        f32x4 f = *(const f32x4*)(W_in + n * NIN + (k - 4224u));        // lo (pairs hiP)
#pragma unroll
        for (int e = 0; e < 4; ++e) v[e] = lo_part(f[e]);
    } else if (k < 4480u) {
        v = *(const f32x4*)(W_in + n * NIN + (k - 4352u));              // hi (pairs loP)
    } else if (k < 4544u) {
        v = *(const f32x4*)(W_out + n * NOUT + (k - 4480u));            // hi
    } else if (k < 4608u) {
        f32x4 f = *(const f32x4*)(W_out + n * NOUT + (k - 4544u));      // lo
#pragma unroll
        for (int e = 0; e < 4; ++e) v[e] = lo_part(f[e]);
    } else {
        v = *(const f32x4*)(W_out + n * NOUT + (k - 4608u));            // hi
    }
    bf16x4 o;
#pragma unroll
    for (int e = 0; e < 4; ++e) o[e] = (__bf16)v[e];
    *(bf16x4*)(Bbuf + (size_t)id * 4u) = o;
}

__global__ __launch_bounds__(512) void gemm_kernel(
    const __bf16* __restrict__ Abuf, const __bf16* __restrict__ Bbuf,
    const float* __restrict__ xin, const float* __restrict__ Bin,
    float* __restrict__ out)
{
    // 3-deep LDS pipeline: 3 x (16KB A + 16KB B) = 96KB
    __shared__ __align__(16) __bf16 As[3][BM * BK];
    __shared__ __align__(16) __bf16 Bs[3][BN * BK];

    const int t  = threadIdx.x;
    const int l  = t & 63;
    const int w  = t >> 6;
    const int wr = w >> 2;   // 0..1  (64-row slab)
    const int wc = w & 3;    // 0..3  (32-col slab)
    const int bm = blockIdx.y;
    const int bn = blockIdx.x;

    f32x4 acc[4][2] = {};

    // Staging: 1024 16B-chunks per tile, 512 threads -> 2 chunks each for A and B.
    // LDS dest LINEAR (global_load_lds requirement); XOR swizzle applied to the
    // global SOURCE column so swizzled ds_reads see correct data (rule #21).
    const __bf16* gA[2];
    const __bf16* gB[2];
    int ldoff[2];
#pragma unroll
    for (int j = 0; j < 2; ++j) {
        int ca  = j * 512 + t;             // chunk id 0..1023
        int row = ca >> 3;                 // 0..127
        int cb  = (ca & 7) << 4;           // byte-in-row 0..112
        int cs  = cb ^ ((row & 7) << 4);   // swizzled source byte
        gA[j] = Abuf + (size_t)(bm * BM + row) * KT + (cs >> 1);
        gB[j] = Bbuf + (size_t)(bn * BN + row) * KT + (cs >> 1);
        ldoff[j] = ca * 16;
    }

#define STAGE(bufi, k0)                                                  \
    do {                                                                 \
        _Pragma("unroll")                                                \
        for (int j = 0; j < 2; ++j) {                                    \
            gload_lds16(gA[j] + (k0), (char*)As[bufi] + ldoff[j]);       \
            gload_lds16(gB[j] + (k0), (char*)Bs[bufi] + ldoff[j]);       \
        }                                                                \
    } while (0)

    // Fragment read byte-offsets (swizzled to match staged layout)
    int offA[4][2], offB[2][2];
#pragma unroll
    for (int m = 0; m < 4; ++m) {
        int row = wr * 64 + m * 16 + (l & 15);
#pragma unroll
        for (int kk = 0; kk < 2; ++kk) {
            int cb = (kk * 64 + ((l >> 4) << 4)) ^ ((row & 7) << 4);
            offA[m][kk] = row * 128 + cb;
        }
    }
#pragma unroll
    for (int n = 0; n < 2; ++n) {
        int row = wc * 32 + n * 16 + (l & 15);
#pragma unroll
        for (int kk = 0; kk < 2; ++kk) {
            int cb = (kk * 64 + ((l >> 4) << 4)) ^ ((row & 7) << 4);
            offB[n][kk] = row * 128 + cb;
        }
    }

#define COMPUTE(bufi)                                                    \
    do {                                                                 \
        _Pragma("unroll")                                                \
        for (int kk = 0; kk < 2; ++kk) {                                 \
            bf16x8 af[4], bv[2];                                         \
            _Pragma("unroll")                                            \
            for (int m = 0; m < 4; ++m)                                  \
                af[m] = *(const bf16x8*)((const char*)As[bufi] + offA[m][kk]); \
            _Pragma("unroll")                                            \
            for (int n = 0; n < 2; ++n)                                  \
                bv[n] = *(const bf16x8*)((const char*)Bs[bufi] + offB[n][kk]); \
            _Pragma("unroll")                                            \
            for (int m = 0; m < 4; ++m)                                  \
                _Pragma("unroll")                                        \
                for (int n = 0; n < 2; ++n)                              \
                    acc[m][n] = __builtin_amdgcn_mfma_f32_16x16x32_bf16( \
                        af[m], bv[n], acc[m][n], 0, 0, 0);               \
        }                                                                \
    } while (0)

    // Prologue: stage tiles 0 and 1, wait for tile 0 (4 newest may remain).
    STAGE(0, 0);
    STAGE(1, BK);
    asm volatile("s_waitcnt vmcnt(4)" ::: "memory");
    __builtin_amdgcn_s_barrier();
    asm volatile("" ::: "memory");

    for (int tt = 0; tt < NT - 1; ++tt) {
        const int cur = tt % 3;
        const int nxt = (tt + 2) % 3;
        if (tt + 2 < NT) {
            STAGE(nxt, (tt + 2) * BK);
            COMPUTE(cur);
            asm volatile("s_waitcnt vmcnt(4)" ::: "memory"); // tile tt+1 landed; tt+2 in flight
        } else {
            COMPUTE(cur);
            asm volatile("s_waitcnt vmcnt(0)" ::: "memory"); // drain last tile
        }
        __builtin_amdgcn_s_barrier();
        asm volatile("" ::: "memory");
    }
    COMPUTE((NT - 1) % 3);

    // Epilogue: out = 0.1*x + 0.9*tanh(acc + B_in)
    // C/D layout: col = lane&15, row = (lane>>4)*4 + reg  [m89/m91-verified]
    const int col0 = bn * BN + wc * 32 + (l & 15);
    const int row0 = bm * BM + wr * 64 + ((l >> 4) << 2);
#pragma unroll
    for (int m = 0; m < 4; ++m) {
#pragma unroll
        for (int i = 0; i < 4; ++i) {
            int r = row0 + m * 16 + i;
            const float* xr   = xin + (size_t)r * NRES;
            float*       orow = out + (size_t)r * NRES;
#pragma unroll
            for (int n = 0; n < 2; ++n) {
                int c = col0 + n * 16;
                float pre = acc[m][n][i] + Bin[c];
                orow[c] = 0.1f * xr[c] + 0.9f * tanhf(pre);
            }
        }
    }
#undef STAGE
#undef COMPUTE
}

extern "C" void kernel_launch(void* const* d_in, const int* in_sizes, int n_in,
                              void* d_out, int out_size, void* d_ws, size_t ws_size,
                              hipStream_t stream) {
    (void)in_sizes; (void)n_in; (void)out_size; (void)ws_size;
    const float* passed     = (const float*)d_in[0];
    const float* lastOutput = (const float*)d_in[1];
    const float* lastPred   = (const float*)d_in[2];
    const float* x          = (const float*)d_in[3];
    const float* prob       = (const float*)d_in[4];
    const float* rand_num   = (const float*)d_in[5];
    const float* W_in       = (const float*)d_in[6];
    const float* W_res      = (const float*)d_in[7];
    const float* W_out      = (const float*)d_in[8];
    const float* B_in       = (const float*)d_in[9];
    float* out = (float*)d_out;

    __bf16* Abuf = (__bf16*)d_ws;                                    // 1024*4672*2 B
    __bf16* Bbuf = (__bf16*)((char*)d_ws + (size_t)NBATCH * KT * 2); // 4096*4672*2 B

    pack_A4<<<(NBATCH * KQ) / 256, 256, 0, stream>>>(
        x, passed, lastOutput, lastPred, prob, rand_num, Abuf);
    pack_B4<<<(NRES * KQ) / 256, 256, 0, stream>>>(
        W_res, W_in, W_out, Bbuf);

    dim3 grid(NRES / BN, NBATCH / BM);
    gemm_kernel<<<grid, 512, 0, stream>>>(Abuf, Bbuf, x, B_in, out);
}